// Round 1
// baseline (787.180 us; speedup 1.0000x reference)
//
#include <hip/hip_runtime.h>
#include <math.h>

#define BB 256
#define VV 50257

// ---------------- Kernel 1: per-row softmax stats (max, 1/sum) ----------------
__global__ __launch_bounds__(1024) void row_stats_kernel(
    const float* __restrict__ w, float2* __restrict__ stats, int V)
{
    const int b = blockIdx.x;
    const float* row = w + (size_t)b * V;

    // branchless online softmax accumulation
    float m = -INFINITY, s = 0.f;
    for (int i = threadIdx.x; i < V; i += blockDim.x) {
        float x = row[i];
        float nm = fmaxf(m, x);
        s = s * __expf(m - nm) + __expf(x - nm);
        m = nm;
    }
    // wave (64-lane) butterfly reduce of (m, s)
    #pragma unroll
    for (int off = 32; off >= 1; off >>= 1) {
        float om = __shfl_xor(m, off, 64);
        float os = __shfl_xor(s, off, 64);
        float nm = fmaxf(m, om);
        s = s * __expf(m - nm) + os * __expf(om - nm);
        m = nm;
    }
    __shared__ float sm[16], ss[16];
    const int wave = threadIdx.x >> 6;
    const int lane = threadIdx.x & 63;
    if (lane == 0) { sm[wave] = m; ss[wave] = s; }
    __syncthreads();
    if (threadIdx.x == 0) {
        const int nw = blockDim.x >> 6;
        float M = sm[0], S = ss[0];
        for (int i = 1; i < nw; ++i) {
            float om = sm[i], os = ss[i];
            float nm = fmaxf(M, om);
            S = S * __expf(M - nm) + os * __expf(om - nm);
            M = nm;
        }
        stats[b] = make_float2(M, 1.0f / S);
    }
}

// ---------------- Kernel 2: weights + scatter-add + transposed store ----------------
#define TV 64   // v-tile
#define TB 32   // b-tile

__global__ __launch_bounds__(256) void weights_kernel(
    const float* __restrict__ w, const int* __restrict__ idx,
    const float2* __restrict__ stats,
    float* __restrict__ avg, float* __restrict__ wT, int Bn, int V)
{
    __shared__ float tile[TV][TB + 1];   // +1 pad: conflict-free transpose
    __shared__ float sm[TB], sinv[TB];

    const int v0 = blockIdx.x * TV;
    const int b0 = blockIdx.y * TB;
    const int tid = threadIdx.x;

    if (tid < TB) {
        float2 st = stats[b0 + tid];
        sm[tid] = st.x; sinv[tid] = st.y;
    }
    __syncthreads();

    const int tx  = tid & 63;   // v offset within tile
    const int ty0 = tid >> 6;   // 0..3
    const int v   = v0 + tx;
    const bool vok = (v < V);

    #pragma unroll
    for (int it = 0; it < TB / 4; ++it) {
        const int bl = ty0 + 4 * it;        // 0..31
        const int b  = b0 + bl;
        float wgt = 0.f;
        if (vok) {
            const size_t base = (size_t)b * V;
            const float x = w[base + v];
            wgt = __expf(x - sm[bl]) * sinv[bl];
            const int id = idx[base + v];
            unsafeAtomicAdd(&avg[base + (size_t)id], wgt);  // HW global_atomic_add_f32
        }
        tile[tx][bl] = wgt;
    }
    __syncthreads();

    // transposed write: wT[v * B + b], coalesced along b
    const int bx  = tid & 31;   // b offset
    const int vy0 = tid >> 5;   // 0..7
    #pragma unroll
    for (int it = 0; it < TV / 8; ++it) {
        const int vr = vy0 + 8 * it;        // 0..63
        const int v2 = v0 + vr;
        if (v2 < V) {
            wT[(size_t)v2 * Bn + b0 + bx] = tile[vr][bx];
        }
    }
}

extern "C" void kernel_launch(void* const* d_in, const int* in_sizes, int n_in,
                              void* d_out, int out_size, void* d_ws, size_t ws_size,
                              hipStream_t stream) {
    const int*   indices = (const int*)d_in[0];
    const float* w_es    = (const float*)d_in[1];
    float* avg = (float*)d_out;
    float* wT  = (float*)d_out + (size_t)BB * VV;
    float2* stats = (float2*)d_ws;

    // zero the scatter-accumulate target (harness poisons d_out with 0xAA)
    hipMemsetAsync(d_out, 0, (size_t)BB * VV * sizeof(float), stream);

    row_stats_kernel<<<BB, 1024, 0, stream>>>(w_es, stats, VV);

    dim3 grid((VV + TV - 1) / TV, BB / TB);
    weights_kernel<<<grid, 256, 0, stream>>>(w_es, indices, stats, avg, wT, BB, VV);
}

// Round 2
// 258.182 us; speedup vs baseline: 3.0489x; 3.0489x over previous
//
#include <hip/hip_runtime.h>
#include <math.h>

#define BB 256
#define VV 50257

// ---------------- Kernel 1: per-row softmax stats (max, 1/sum), two-pass ----------------
__global__ __launch_bounds__(1024) void row_stats_kernel(
    const float* __restrict__ w, float2* __restrict__ stats, int V)
{
    const int b = blockIdx.x;
    const float* row = w + (size_t)b * V;
    const int tid = threadIdx.x, nt = 1024;

    // 16B-alignment prologue
    const int a = (int)(((16u - ((uintptr_t)row & 15u)) & 15u) >> 2);
    const int nv4 = (V - a) >> 2;
    const float4* rv = (const float4*)(row + a);
    const int tail0 = a + (nv4 << 2);

    // pass 1: max
    float m = -INFINITY;
    for (int i = tid; i < a; i += nt) m = fmaxf(m, row[i]);
    for (int i = tail0 + tid; i < V; i += nt) m = fmaxf(m, row[i]);
    for (int i = tid; i < nv4; i += nt) {
        float4 v = rv[i];
        m = fmaxf(fmaxf(m, v.x), fmaxf(v.y, fmaxf(v.z, v.w)));
    }
    #pragma unroll
    for (int off = 32; off >= 1; off >>= 1) m = fmaxf(m, __shfl_xor(m, off, 64));
    __shared__ float sred[16];
    __shared__ float ssum[16];
    const int wave = tid >> 6, lane = tid & 63;
    if (lane == 0) sred[wave] = m;
    __syncthreads();
    float M = sred[0];
    #pragma unroll
    for (int i = 1; i < 16; ++i) M = fmaxf(M, sred[i]);

    // pass 2: sum of exp (row is L2-resident now)
    float s = 0.f;
    for (int i = tid; i < a; i += nt) s += __expf(row[i] - M);
    for (int i = tail0 + tid; i < V; i += nt) s += __expf(row[i] - M);
    for (int i = tid; i < nv4; i += nt) {
        float4 v = rv[i];
        s += __expf(v.x - M) + __expf(v.y - M) + __expf(v.z - M) + __expf(v.w - M);
    }
    #pragma unroll
    for (int off = 32; off >= 1; off >>= 1) s += __shfl_xor(s, off, 64);
    if (lane == 0) ssum[wave] = s;
    __syncthreads();
    if (tid == 0) {
        float S = 0.f;
        #pragma unroll
        for (int i = 0; i < 16; ++i) S += ssum[i];
        stats[b] = make_float2(M, 1.0f / S);
    }
}

// ---------------- Kernel 2: LDS scatter-accumulate, quarter-range per block ----------------
#define NRANGE 4
#define QSZ 12565   // ceil(50257/4)

__global__ __launch_bounds__(512) void scatter_kernel(
    const float* __restrict__ w, const int* __restrict__ idx,
    const float2* __restrict__ stats, float* __restrict__ avg, int V)
{
    __shared__ float acc[QSZ];

    // swizzle: the 4 quarter-blocks of a row land on the same XCD (bid%8)
    const int bid  = blockIdx.x;        // 0..1023
    const int xcd  = bid & 7;
    const int slot = bid >> 3;          // 0..127
    const int row  = xcd + 8 * (slot >> 2);
    const int q    = slot & 3;
    const int lo   = q * QSZ;
    const int hi   = min(V, lo + QSZ);
    const int tid  = threadIdx.x, nt = 512;

    for (int i = tid; i < QSZ; i += nt) acc[i] = 0.f;
    const float2 st = stats[row];
    const float M = st.x, inv = st.y;
    __syncthreads();

    const size_t base = (size_t)row * V;
    const float* wr = w + base;
    const int*   ir = idx + base;
    const int a = (int)(((16u - ((uintptr_t)wr & 15u)) & 15u) >> 2);
    const int nv4 = (V - a) >> 2;
    const int tail0 = a + (nv4 << 2);
    const float4* wv4 = (const float4*)(wr + a);
    const int4*   iv4 = (const int4*)(ir + a);

    // scalar prologue + tail
    for (int i = tid; i < a; i += nt) {
        const int id = ir[i];
        if (id >= lo && id < hi) atomicAdd(&acc[id - lo], __expf(wr[i] - M) * inv);
    }
    for (int i = tail0 + tid; i < V; i += nt) {
        const int id = ir[i];
        if (id >= lo && id < hi) atomicAdd(&acc[id - lo], __expf(wr[i] - M) * inv);
    }
    // vec4 main loop
    for (int i = tid; i < nv4; i += nt) {
        const float4 xv = wv4[i];
        const int4   id = iv4[i];
        if (id.x >= lo && id.x < hi) atomicAdd(&acc[id.x - lo], __expf(xv.x - M) * inv);
        if (id.y >= lo && id.y < hi) atomicAdd(&acc[id.y - lo], __expf(xv.y - M) * inv);
        if (id.z >= lo && id.z < hi) atomicAdd(&acc[id.z - lo], __expf(xv.z - M) * inv);
        if (id.w >= lo && id.w < hi) atomicAdd(&acc[id.w - lo], __expf(xv.w - M) * inv);
    }
    __syncthreads();

    // coalesced contiguous store of this range
    for (int i = tid; i < hi - lo; i += nt) avg[base + lo + i] = acc[i];
}

// ---------------- Kernel 3: weights^T via LDS transpose tile ----------------
#define T3V 64
#define T3B 64

__global__ __launch_bounds__(256) void transpose_kernel(
    const float* __restrict__ w, const float2* __restrict__ stats,
    float* __restrict__ wT, int Bn, int V)
{
    __shared__ float tile[T3V][T3B + 1];
    __shared__ float sM[T3B], sI[T3B];

    const int v0 = blockIdx.x * T3V;
    const int b0 = blockIdx.y * T3B;
    const int tid = threadIdx.x;

    if (tid < T3B) { float2 st = stats[b0 + tid]; sM[tid] = st.x; sI[tid] = st.y; }
    __syncthreads();

    const int tx = tid & 63;   // v offset
    const int ty = tid >> 6;   // 0..3
    const int v  = v0 + tx;
    const bool vok = (v < V);

    #pragma unroll
    for (int it = 0; it < T3B / 4; ++it) {
        const int bl = ty + 4 * it;
        float wgt = 0.f;
        if (vok) {
            const float x = w[(size_t)(b0 + bl) * V + v];
            wgt = __expf(x - sM[bl]) * sI[bl];
        }
        tile[tx][bl] = wgt;
    }
    __syncthreads();

    const int bx = tid & 63;   // b offset (64 consecutive -> 256B stores)
    const int vy = tid >> 6;
    #pragma unroll
    for (int it = 0; it < T3V / 4; ++it) {
        const int vr = vy + 4 * it;
        const int v2 = v0 + vr;
        if (v2 < V) wT[(size_t)v2 * Bn + b0 + bx] = tile[vr][bx];
    }
}

extern "C" void kernel_launch(void* const* d_in, const int* in_sizes, int n_in,
                              void* d_out, int out_size, void* d_ws, size_t ws_size,
                              hipStream_t stream) {
    const int*   indices = (const int*)d_in[0];
    const float* w_es    = (const float*)d_in[1];
    float* avg = (float*)d_out;
    float* wT  = (float*)d_out + (size_t)BB * VV;
    float2* stats = (float2*)d_ws;

    row_stats_kernel<<<BB, 1024, 0, stream>>>(w_es, stats, VV);

    scatter_kernel<<<BB * NRANGE, 512, 0, stream>>>(w_es, indices, stats, avg, VV);

    dim3 g3((VV + T3V - 1) / T3V, BB / T3B);
    transpose_kernel<<<g3, 256, 0, stream>>>(w_es, stats, wT, BB, VV);
}

// Round 3
// 250.029 us; speedup vs baseline: 3.1484x; 1.0326x over previous
//
#include <hip/hip_runtime.h>
#include <math.h>

#define BB 256
#define VV 50257

// ---------------- Kernel 1: per-row softmax stats (max, 1/sum), two-pass ----------------
__global__ __launch_bounds__(1024) void row_stats_kernel(
    const float* __restrict__ w, float2* __restrict__ stats, int V)
{
    const int b = blockIdx.x;
    const float* row = w + (size_t)b * V;
    const int tid = threadIdx.x; const int nt = 1024;

    // 16B-alignment prologue
    const int a = (int)(((16u - ((uintptr_t)row & 15u)) & 15u) >> 2);
    const int nv4 = (V - a) >> 2;
    const float4* rv = (const float4*)(row + a);
    const int tail0 = a + (nv4 << 2);

    // pass 1: max (4 independent accumulators for MLP)
    float m0 = -INFINITY, m1 = -INFINITY, m2 = -INFINITY, m3 = -INFINITY;
    for (int i = tid; i < a; i += nt) m0 = fmaxf(m0, row[i]);
    for (int i = tail0 + tid; i < V; i += nt) m0 = fmaxf(m0, row[i]);
    {
        int i = tid;
        for (; i + 3 * nt < nv4; i += 4 * nt) {
            float4 v0 = rv[i], v1 = rv[i + nt], v2 = rv[i + 2 * nt], v3 = rv[i + 3 * nt];
            m0 = fmaxf(m0, fmaxf(fmaxf(v0.x, v0.y), fmaxf(v0.z, v0.w)));
            m1 = fmaxf(m1, fmaxf(fmaxf(v1.x, v1.y), fmaxf(v1.z, v1.w)));
            m2 = fmaxf(m2, fmaxf(fmaxf(v2.x, v2.y), fmaxf(v2.z, v2.w)));
            m3 = fmaxf(m3, fmaxf(fmaxf(v3.x, v3.y), fmaxf(v3.z, v3.w)));
        }
        for (; i < nv4; i += nt) {
            float4 v0 = rv[i];
            m0 = fmaxf(m0, fmaxf(fmaxf(v0.x, v0.y), fmaxf(v0.z, v0.w)));
        }
    }
    float m = fmaxf(fmaxf(m0, m1), fmaxf(m2, m3));
    #pragma unroll
    for (int off = 32; off >= 1; off >>= 1) m = fmaxf(m, __shfl_xor(m, off, 64));
    __shared__ float sred[16];
    __shared__ float ssum[16];
    const int wave = tid >> 6, lane = tid & 63;
    if (lane == 0) sred[wave] = m;
    __syncthreads();
    float M = sred[0];
    #pragma unroll
    for (int i = 1; i < 16; ++i) M = fmaxf(M, sred[i]);

    // pass 2: sum of exp (row now L2/L3-resident)
    float s0 = 0.f, s1 = 0.f, s2 = 0.f, s3 = 0.f;
    for (int i = tid; i < a; i += nt) s0 += __expf(row[i] - M);
    for (int i = tail0 + tid; i < V; i += nt) s0 += __expf(row[i] - M);
    {
        int i = tid;
        for (; i + 3 * nt < nv4; i += 4 * nt) {
            float4 v0 = rv[i], v1 = rv[i + nt], v2 = rv[i + 2 * nt], v3 = rv[i + 3 * nt];
            s0 += __expf(v0.x - M) + __expf(v0.y - M) + __expf(v0.z - M) + __expf(v0.w - M);
            s1 += __expf(v1.x - M) + __expf(v1.y - M) + __expf(v1.z - M) + __expf(v1.w - M);
            s2 += __expf(v2.x - M) + __expf(v2.y - M) + __expf(v2.z - M) + __expf(v2.w - M);
            s3 += __expf(v3.x - M) + __expf(v3.y - M) + __expf(v3.z - M) + __expf(v3.w - M);
        }
        for (; i < nv4; i += nt) {
            float4 v0 = rv[i];
            s0 += __expf(v0.x - M) + __expf(v0.y - M) + __expf(v0.z - M) + __expf(v0.w - M);
        }
    }
    float s = (s0 + s1) + (s2 + s3);
    #pragma unroll
    for (int off = 32; off >= 1; off >>= 1) s += __shfl_xor(s, off, 64);
    if (lane == 0) ssum[wave] = s;
    __syncthreads();
    if (tid == 0) {
        float S = 0.f;
        #pragma unroll
        for (int i = 0; i < 16; ++i) S += ssum[i];
        stats[b] = make_float2(M, 1.0f / S);
    }
}

// ---------------- Kernel 2: LDS scatter-accumulate, quarter-range per block ----------------
#define NRANGE 4
#define QSZ 12565   // ceil(50257/4)

__global__ __launch_bounds__(512) void scatter_kernel(
    const float* __restrict__ w, const int* __restrict__ idx,
    const float2* __restrict__ stats, float* __restrict__ avg, int V)
{
    __shared__ float acc[QSZ];

    // swizzle: the 4 quarter-blocks of a row land on the same XCD (bid%8)
    const int bid  = blockIdx.x;        // 0..1023
    const int xcd  = bid & 7;
    const int slot = bid >> 3;          // 0..127
    const int row  = xcd + 8 * (slot >> 2);
    const int q    = slot & 3;
    const int lo   = q * QSZ;
    const int hi   = min(V, lo + QSZ);
    const unsigned range = (unsigned)(hi - lo);
    const int tid  = threadIdx.x; const int nt = 512;

    for (int i = tid; i < QSZ; i += nt) acc[i] = 0.f;
    const float2 st = stats[row];
    const float M = st.x, inv = st.y;
    __syncthreads();

    const size_t base = (size_t)row * V;
    const float* wr = w + base;
    const int*   ir = idx + base;
    const int a = (int)(((16u - ((uintptr_t)wr & 15u)) & 15u) >> 2);
    const int nv4 = (V - a) >> 2;
    const int tail0 = a + (nv4 << 2);
    const float4* wv4 = (const float4*)(wr + a);
    const int4*   iv4 = (const int4*)(ir + a);

#define PROC1(idv, xv)                                                     \
    do {                                                                   \
        unsigned off = (unsigned)((idv) - lo);                             \
        if (off < range) atomicAdd(&acc[off], __expf((xv) - M) * inv);     \
    } while (0)
#define PROC4(iv, xv)                                                      \
    do {                                                                   \
        PROC1((iv).x, (xv).x); PROC1((iv).y, (xv).y);                      \
        PROC1((iv).z, (xv).z); PROC1((iv).w, (xv).w);                      \
    } while (0)

    // scalar prologue + tail
    for (int i = tid; i < a; i += nt) PROC1(ir[i], wr[i]);
    for (int i = tail0 + tid; i < V; i += nt) PROC1(ir[i], wr[i]);

    // vec4 main loop, 4-deep unroll: 8 vector loads in flight
    {
        int i = tid;
        for (; i + 3 * nt < nv4; i += 4 * nt) {
            int4   i0 = iv4[i], i1 = iv4[i + nt], i2 = iv4[i + 2 * nt], i3 = iv4[i + 3 * nt];
            float4 x0 = wv4[i], x1 = wv4[i + nt], x2 = wv4[i + 2 * nt], x3 = wv4[i + 3 * nt];
            PROC4(i0, x0); PROC4(i1, x1); PROC4(i2, x2); PROC4(i3, x3);
        }
        for (; i < nv4; i += nt) {
            int4 i0 = iv4[i]; float4 x0 = wv4[i];
            PROC4(i0, x0);
        }
    }
    __syncthreads();

    // coalesced contiguous store of this range (streaming, no reuse)
    for (int i = tid; i < hi - lo; i += nt)
        __builtin_nontemporal_store(acc[i], &avg[base + lo + i]);
#undef PROC1
#undef PROC4
}

// ---------------- Kernel 3: weights^T via LDS transpose tile ----------------
#define T3V 64
#define T3B 64

__global__ __launch_bounds__(256) void transpose_kernel(
    const float* __restrict__ w, const float2* __restrict__ stats,
    float* __restrict__ wT, int Bn, int V)
{
    __shared__ float tile[T3V][T3B + 1];
    __shared__ float sM[T3B], sI[T3B];

    const int v0 = blockIdx.x * T3V;
    const int b0 = blockIdx.y * T3B;
    const int tid = threadIdx.x;

    if (tid < T3B) { float2 st = stats[b0 + tid]; sM[tid] = st.x; sI[tid] = st.y; }
    __syncthreads();

    const int tx = tid & 63;   // v offset
    const int ty = tid >> 6;   // 0..3
    const int v  = v0 + tx;
    const bool vok = (v < V);

    #pragma unroll
    for (int it = 0; it < T3B / 4; ++it) {
        const int bl = ty + 4 * it;
        float wgt = 0.f;
        if (vok) {
            const float x = w[(size_t)(b0 + bl) * V + v];
            wgt = __expf(x - sM[bl]) * sI[bl];
        }
        tile[tx][bl] = wgt;
    }
    __syncthreads();

    const int bx = tid & 63;   // b offset (64 consecutive -> 256B stores)
    const int vy = tid >> 6;
    #pragma unroll
    for (int it = 0; it < T3V / 4; ++it) {
        const int vr = vy + 4 * it;
        const int v2 = v0 + vr;
        if (v2 < V) __builtin_nontemporal_store(tile[vr][bx], &wT[(size_t)v2 * Bn + b0 + bx]);
    }
}

extern "C" void kernel_launch(void* const* d_in, const int* in_sizes, int n_in,
                              void* d_out, int out_size, void* d_ws, size_t ws_size,
                              hipStream_t stream) {
    const int*   indices = (const int*)d_in[0];
    const float* w_es    = (const float*)d_in[1];
    float* avg = (float*)d_out;
    float* wT  = (float*)d_out + (size_t)BB * VV;
    float2* stats = (float2*)d_ws;

    row_stats_kernel<<<BB, 1024, 0, stream>>>(w_es, stats, VV);

    scatter_kernel<<<BB * NRANGE, 512, 0, stream>>>(w_es, indices, stats, avg, VV);

    dim3 g3((VV + T3V - 1) / T3V, BB / T3B);
    transpose_kernel<<<g3, 256, 0, stream>>>(w_es, stats, wT, BB, VV);
}